// Round 5
// baseline (208.355 us; speedup 1.0000x reference)
//
#include <hip/hip_runtime.h>
#include <hip/hip_bf16.h>

using bf16 = __hip_bfloat16;
typedef __attribute__((ext_vector_type(8))) short short8;
typedef __attribute__((ext_vector_type(4))) short s4v;
typedef __attribute__((ext_vector_type(4))) float float4v;
typedef __attribute__((ext_vector_type(4))) float f32x4;

#define MFMA16(a, b, c) __builtin_amdgcn_mfma_f32_16x16x32_bf16((a), (b), (c), 0, 0, 0)

// async global->LDS, 16B per lane, dest = wave-uniform base + lane*16
#define GLD_LDS16(g, l)                                            \
    __builtin_amdgcn_global_load_lds(                              \
        (const __attribute__((address_space(1))) void*)(g),        \
        (__attribute__((address_space(3))) void*)(l), 16, 0, 0)

constexpr int Bc = 2;
constexpr int Sc = 2048;
constexpr int Hc = 16;
constexpr int DKc = 64;
constexpr int Dc = 1024;
constexpr size_t MEG = 1024 * 1024;

union BFU { bf16 h; short s; };

__device__ inline short bfbits(float f) {
    BFU u; u.h = __float2bfloat16(f); return u.s;
}

__device__ inline float bits2f(short s) {
    BFU u; u.s = s; return __bfloat162float(u.h);
}

__device__ inline short8 load_cvt8(const float* __restrict__ p) {
    f32x4 a = *(const f32x4*)p;
    f32x4 b = *(const f32x4*)(p + 4);
    short8 r;
    r[0] = bfbits(a[0]); r[1] = bfbits(a[1]); r[2] = bfbits(a[2]); r[3] = bfbits(a[3]);
    r[4] = bfbits(b[0]); r[5] = bfbits(b[1]); r[6] = bfbits(b[2]); r[7] = bfbits(b[3]);
    return r;
}

// ---------------------------------------------------------------------------
// One-shot fp32 -> bf16 conversion of x, Wq, Wk, Wv, Wo (8M elems) into ws.
// ---------------------------------------------------------------------------
__global__ __launch_bounds__(256) void cvt_kernel(
    const float* __restrict__ x, const float* __restrict__ Wq,
    const float* __restrict__ Wk, const float* __restrict__ Wv,
    const float* __restrict__ Wo, bf16* __restrict__ dst)
{
    const size_t i = ((size_t)blockIdx.x * 256 + threadIdx.x) * 8;
    const float* s;
    if      (i < 4 * MEG) s = x  + i;
    else if (i < 5 * MEG) s = Wq + (i - 4 * MEG);
    else if (i < 6 * MEG) s = Wk + (i - 5 * MEG);
    else if (i < 7 * MEG) s = Wv + (i - 6 * MEG);
    else                  s = Wo + (i - 7 * MEG);
    *(short8*)(dst + i) = load_cvt8(s);
}

// ---------------------------------------------------------------------------
// Fused QKV projection, m97-style BK=32. grid (24, 32): sel = bx>>3,
// ntile = bx&7. Q pre-scaled by (1/8)*log2e. V^T stores packed to 8B.
// ---------------------------------------------------------------------------
__global__ __launch_bounds__(256) void qkv_gemm_kernel(
    const bf16* __restrict__ x,
    const bf16* __restrict__ Wq, const float* __restrict__ bq,
    const bf16* __restrict__ Wk, const float* __restrict__ bk,
    const bf16* __restrict__ Wv, const float* __restrict__ bv,
    bf16* __restrict__ q_ws, bf16* __restrict__ k_ws, bf16* __restrict__ v_ws)
{
    constexpr int BM = 128, BN = 128, BK = 32;
    __shared__ __align__(16) bf16 sA[BM * BK];
    __shared__ __align__(16) bf16 sB[BN * BK];

    const int bx = blockIdx.x;
    const int sel = bx >> 3;               // 0=Q 1=K 2=V
    const int n0 = (bx & 7) * BN;
    const int m0 = blockIdx.y * BM;

    const bf16* __restrict__ Wsel = (sel == 0) ? Wq : ((sel == 1) ? Wk : Wv);
    const float* __restrict__ bsel = (sel == 0) ? bq : ((sel == 1) ? bk : bv);

    const int t = threadIdx.x;
    const int lane = t & 63;
    const int wave = t >> 6;
    const int ln = lane & 15;
    const int qd = lane >> 4;
    const int wm = (wave >> 1) * 64;
    const int wn = (wave & 1) * 64;

    const int gr = lane >> 2;              // 0..15: row within 16-row chunk
    const int gc = (lane & 3) * 8;         // 0,8,16,24

    float4v acc[4][4];
#pragma unroll
    for (int i = 0; i < 4; i++)
#pragma unroll
        for (int j = 0; j < 4; j++) acc[i][j] = (float4v)0.0f;

    for (int kk = 0; kk < Dc; kk += BK) {
        __syncthreads();
#pragma unroll
        for (int cc = 0; cc < 2; cc++) {
            const int c = wave * 2 + cc;
            GLD_LDS16(x    + (size_t)(m0 + c * 16 + gr) * Dc + kk + gc, &sA[c * 512]);
            GLD_LDS16(Wsel + (size_t)(n0 + c * 16 + gr) * Dc + kk + gc, &sB[c * 512]);
        }
        __syncthreads();

        short8 af[4], wf[4];
#pragma unroll
        for (int i = 0; i < 4; i++)
            af[i] = *(const short8*)&sA[(wm + i * 16 + ln) * BK + qd * 8];
#pragma unroll
        for (int j = 0; j < 4; j++)
            wf[j] = *(const short8*)&sB[(wn + j * 16 + ln) * BK + qd * 8];
#pragma unroll
        for (int i = 0; i < 4; i++)
#pragma unroll
            for (int j = 0; j < 4; j++)
                acc[i][j] = MFMA16(af[i], wf[j], acc[i][j]);
    }

    constexpr float QSCALE = 0.125f * 1.44269504088896f;

#pragma unroll
    for (int j = 0; j < 4; j++) {
        const int n = n0 + wn + j * 16 + ln;
        const float bias = bsel[n];
        const int h_ = n >> 6, d_ = n & 63;
#pragma unroll
        for (int i = 0; i < 4; i++) {
            const int mbase = m0 + wm + i * 16 + qd * 4;
            if (sel == 2) {                // V^T: 4 s-contiguous -> one 8B store
                const int b_ = mbase >> 11, s_ = mbase & 2047;
                s4v pk;
#pragma unroll
                for (int r = 0; r < 4; r++)
                    pk[r] = bfbits(acc[i][j][r] + bias);
                *(s4v*)&v_ws[(((size_t)(b_ * Hc + h_)) * DKc + d_) * Sc + s_] = pk;
            } else {
#pragma unroll
                for (int r = 0; r < 4; r++) {
                    const int m = mbase + r;
                    const int b_ = m >> 11, s_ = m & 2047;
                    float v = acc[i][j][r] + bias;
                    if (sel == 0) v *= QSCALE;
                    const bf16 o = __float2bfloat16(v);
                    if (sel == 0)
                        q_ws[(((size_t)(b_ * Hc + h_)) * Sc + s_) * DKc + d_] = o;
                    else
                        k_ws[(((size_t)(b_ * Hc + h_)) * Sc + s_) * DKc + d_] = o;
                }
            }
        }
    }
}

// ---------------------------------------------------------------------------
// Flash attention v8: SPLIT-S. Round-4 showed occupancy is grid-capped (512
// blocks = exactly 2/CU) while LDS (52,224 B) fits 3/CU — and v5 proved TLP
// is the binding resource. Split each (bh,qt) tile's key range in half:
// grid (32, 16, 2) = 1024 blocks, 16 ktiles each -> 3 blocks/CU resident,
// 24 waves/CU (1.5x TLP). No running max is used, so partials combine
// exactly: each split stores NORMALIZED partial O_s (bf16, O(1) magnitude)
// plus denominator l_s (f32); combine_kernel computes
// O = (l0*O0 + l1*O1)/(l0+l1). Kept: Q-in-registers, conflict-free sP
// (LQP=76), xor-swizzled async dbuf K/V, ONE barrier/ktile, swapped-operand
// QK^T, ones-column denominator, setprio (3 independent blocks/CU = phase
// diversity, the regime where setprio measured positive).
// ---------------------------------------------------------------------------
__global__ __launch_bounds__(512, 6) void attn_kernel(
    const bf16* __restrict__ q_ws, const bf16* __restrict__ k_ws,
    const bf16* __restrict__ v_ws, bf16* __restrict__ po0,
    bf16* __restrict__ po1, float* __restrict__ l_ws)
{
    constexpr int LQP = 76;  // short row stride for sP (152 B, conflict-free)
    constexpr int NKT = 16;  // 16 ktiles of 64 keys = 1024 keys per split
    __shared__ __align__(16) bf16 sK[2][64 * 64];    // swizzled dbuf
    __shared__ __align__(16) bf16 sV[2][64 * 64];    // V^T [d][key], swizzled dbuf
    __shared__ __align__(16) short sP[8][16 * LQP];  // per-wave P [qrow][key]

    const int bh = blockIdx.x;
    const int qt = blockIdx.y;
    const int sp = blockIdx.z;             // key-range split 0/1
    const int t = threadIdx.x;
    const int lane = t & 63;
    const int wave = t >> 6;               // 0..7
    const int ln = lane & 15;
    const int qd = lane >> 4;
    short* const sPw = sP[wave];

    const bf16* __restrict__ Qbase = q_ws + (size_t)bh * Sc * DKc + qt * 128 * DKc;
    const bf16* __restrict__ Kbase = k_ws + ((size_t)bh * Sc + sp * 1024) * DKc;
    const bf16* __restrict__ Vbase = v_ws + (size_t)bh * DKc * Sc + sp * 1024;

    const int rloc = lane >> 3;            // 0..7 row within 8-row chunk
    const int blk = lane & 7;              // LDS 16B-block index

    // Q B-frags direct global->register, loop-invariant (8 VGPRs).
    // lane holds Q[qrow = wave*16 + ln][k = ks*32 + qd*8 .. +7]
    short8 qf[2];
#pragma unroll
    for (int ks = 0; ks < 2; ks++)
        qf[ks] = *(const short8*)
            (Qbase + (size_t)(wave * 16 + ln) * DKc + ks * 32 + qd * 8);

    {   // stage K/V tile 0 async: 8 chunks each, one per wave
        const int row = wave * 8 + rloc;
        const int gb = blk ^ (row & 7);
        GLD_LDS16(Kbase + (size_t)row * DKc + gb * 8, &sK[0][wave * 512]);
        GLD_LDS16(Vbase + (size_t)row * Sc + gb * 8, &sV[0][wave * 512]);
    }

    // constant ones B-frag: B[n=ln][k]=1 iff ln==0 (denominator column)
    short8 ones8;
    {
        const short ob = (ln == 0) ? (short)0x3F80 : (short)0;
#pragma unroll
        for (int i = 0; i < 8; i++) ones8[i] = ob;
    }

    float4v oacc[5];
#pragma unroll
    for (int j = 0; j < 5; j++) oacc[j] = (float4v)0.0f;

    for (int kt = 0; kt < NKT; kt++) {
        const int cur = kt & 1;
        __syncthreads();   // drains vmcnt: buf[cur] ready; prior reads done
        if (kt + 1 < NKT) {        // prefetch next tile into the other buffer
            const int nxt = (kt + 1) & 1;
            const int row = wave * 8 + rloc;
            const int gb = blk ^ (row & 7);
            GLD_LDS16(Kbase + (size_t)((kt + 1) * 64 + row) * DKc + gb * 8,
                      &sK[nxt][wave * 512]);
            GLD_LDS16(Vbase + (size_t)row * Sc + (kt + 1) * 64 + gb * 8,
                      &sV[nxt][wave * 512]);
        }

        // S^T = K Q^T: A=K[m=key], B=Q[n=qrow]; C col=qrow(ln), row=key(qd*4+r)
        float4v sacc[4];
#pragma unroll
        for (int j = 0; j < 4; j++) sacc[j] = (float4v)0.0f;
        __builtin_amdgcn_s_setprio(1);
#pragma unroll
        for (int ks = 0; ks < 2; ks++) {
#pragma unroll
            for (int j = 0; j < 4; j++) {
                const int row = j * 16 + ln;
                const short8 ak = *(const short8*)
                    &sK[cur][row * 64 + (((ks * 4 + qd) ^ (row & 7)) << 3)];
                sacc[j] = MFMA16(ak, qf[ks], sacc[j]);
            }
        }
        __builtin_amdgcn_s_setprio(0);

        // P = exp2(S^T) -> sP [qrow][key]: lane holds qrow=ln, keys 4-contig.
#pragma unroll
        for (int j = 0; j < 4; j++) {
            s4v pk;
#pragma unroll
            for (int r = 0; r < 4; r++)
                pk[r] = bfbits(exp2f(sacc[j][r]));
            *(s4v*)&sPw[ln * LQP + j * 16 + qd * 4] = pk;
        }

        // O += P V: A=P[m=qrow], B=V^T[n=d]; ones-frag accumulates denominator.
        __builtin_amdgcn_s_setprio(1);
#pragma unroll
        for (int ks = 0; ks < 2; ks++) {
            // two b64 reads -> register-pair concat (no element inserts)
            const s4v p0 = *(const s4v*)&sPw[ln * LQP + ks * 32 + qd * 8];
            const s4v p1 = *(const s4v*)&sPw[ln * LQP + ks * 32 + qd * 8 + 4];
            const short8 ap = __builtin_shufflevector(p0, p1, 0, 1, 2, 3, 4, 5, 6, 7);
#pragma unroll
            for (int j = 0; j < 4; j++) {
                const int row = j * 16 + ln;
                const short8 bv_ = *(const short8*)
                    &sV[cur][row * 64 + (((ks * 4 + qd) ^ (row & 7)) << 3)];
                oacc[j] = MFMA16(ap, bv_, oacc[j]);
            }
            oacc[4] = MFMA16(ap, ones8, oacc[4]);
        }
        __builtin_amdgcn_s_setprio(0);
    }

    // denominator = col n=0 of oacc[4] => lanes ln==0. Store l_s, then
    // normalize this split's partial O and store it.
    const int b_ = bh >> 4, h_ = bh & 15;
    bf16* __restrict__ po = sp ? po1 : po0;
    if (ln == 0) {
#pragma unroll
        for (int r = 0; r < 4; r++)
            l_ws[(size_t)(sp * 32 + bh) * Sc + qt * 128 + wave * 16 + qd * 4 + r] =
                oacc[4][r];
    }
#pragma unroll
    for (int r = 0; r < 4; r++) {
        const float l = __shfl(oacc[4][r], lane & 48, 64);
        const float inv = 1.0f / l;
        const int s_ = qt * 128 + wave * 16 + qd * 4 + r;
#pragma unroll
        for (int j = 0; j < 4; j++) {
            const int d_ = j * 16 + ln;
            po[(((size_t)(b_ * Sc + s_)) * Hc + h_) * DKc + d_] =
                __float2bfloat16(oacc[j][r] * inv);
        }
    }
}

// ---------------------------------------------------------------------------
// Combine the two split-S partials: O = (l0*O0 + l1*O1)/(l0+l1), elementwise
// over (b,s,h,d); writes final bf16 into po0 (= ao_ws) in place.
// grid 2048 x 256 threads, 8 elems/thread (one short8).
// ---------------------------------------------------------------------------
__global__ __launch_bounds__(256) void combine_kernel(
    bf16* po0, const bf16* __restrict__ po1, const float* __restrict__ l_ws)
{
    const size_t gid = (size_t)blockIdx.x * 256 + threadIdx.x;
    const size_t e = gid * 8;              // 8 d-elems within one (b,s,h) row
    const int flat = (int)(e >> 6);        // (b*Sc + s)*Hc + h
    const int h_ = flat & 15;
    const int bs = flat >> 4;
    const int b_ = bs >> 11, s_ = bs & 2047;
    const int bh = b_ * Hc + h_;
    const float l0 = l_ws[(size_t)bh * Sc + s_];
    const float l1 = l_ws[(size_t)(32 + bh) * Sc + s_];
    const float inv = 1.0f / (l0 + l1);
    const float w0 = l0 * inv, w1 = l1 * inv;
    const short8 a = *(const short8*)(po0 + e);
    const short8 b = *(const short8*)(po1 + e);
    short8 o;
#pragma unroll
    for (int i = 0; i < 8; i++)
        o[i] = bfbits(bits2f(a[i]) * w0 + bits2f(b[i]) * w1);
    *(short8*)(po0 + e) = o;
}

// ---------------------------------------------------------------------------
// Output projection, m97-style BK=32. grid (8, 32), block 256.
// ---------------------------------------------------------------------------
__global__ __launch_bounds__(256) void out_gemm_kernel(
    const bf16* __restrict__ A, const bf16* __restrict__ Wo,
    const float* __restrict__ bo, float* __restrict__ out)
{
    constexpr int BM = 128, BN = 128, BK = 32;
    __shared__ __align__(16) bf16 sA[BM * BK];
    __shared__ __align__(16) bf16 sB[BN * BK];

    const int n0 = blockIdx.x * BN;
    const int m0 = blockIdx.y * BM;

    const int t = threadIdx.x;
    const int lane = t & 63;
    const int wave = t >> 6;
    const int ln = lane & 15;
    const int qd = lane >> 4;
    const int wm = (wave >> 1) * 64;
    const int wn = (wave & 1) * 64;

    const int gr = lane >> 2;
    const int gc = (lane & 3) * 8;

    float4v acc[4][4];
#pragma unroll
    for (int i = 0; i < 4; i++)
#pragma unroll
        for (int j = 0; j < 4; j++) acc[i][j] = (float4v)0.0f;

    for (int kk = 0; kk < Dc; kk += BK) {
        __syncthreads();
#pragma unroll
        for (int cc = 0; cc < 2; cc++) {
            const int c = wave * 2 + cc;
            GLD_LDS16(A  + (size_t)(m0 + c * 16 + gr) * Dc + kk + gc, &sA[c * 512]);
            GLD_LDS16(Wo + (size_t)(n0 + c * 16 + gr) * Dc + kk + gc, &sB[c * 512]);
        }
        __syncthreads();

        short8 af[4], wf[4];
#pragma unroll
        for (int i = 0; i < 4; i++)
            af[i] = *(const short8*)&sA[(wm + i * 16 + ln) * BK + qd * 8];
#pragma unroll
        for (int j = 0; j < 4; j++)
            wf[j] = *(const short8*)&sB[(wn + j * 16 + ln) * BK + qd * 8];
#pragma unroll
        for (int i = 0; i < 4; i++)
#pragma unroll
            for (int j = 0; j < 4; j++)
                acc[i][j] = MFMA16(af[i], wf[j], acc[i][j]);
    }

#pragma unroll
    for (int j = 0; j < 4; j++) {
        const int n = n0 + wn + j * 16 + ln;
        const float bias = bo[n];
#pragma unroll
        for (int i = 0; i < 4; i++) {
            const int mbase = m0 + wm + i * 16 + qd * 4;
#pragma unroll
            for (int r = 0; r < 4; r++) {
                const int m = mbase + r;
                out[(size_t)m * Dc + n] = acc[i][j][r] + bias;
            }
        }
    }
}

// ---------------------------------------------------------------------------
extern "C" void kernel_launch(void* const* d_in, const int* in_sizes, int n_in,
                              void* d_out, int out_size, void* d_ws, size_t ws_size,
                              hipStream_t stream)
{
    const float* x  = (const float*)d_in[0];
    const float* Wq = (const float*)d_in[1];
    const float* bq = (const float*)d_in[2];
    const float* Wk = (const float*)d_in[3];
    const float* bk = (const float*)d_in[4];
    const float* Wv = (const float*)d_in[5];
    const float* bv = (const float*)d_in[6];
    const float* Wo = (const float*)d_in[7];
    const float* bo = (const float*)d_in[8];
    float* out = (float*)d_out;

    bf16* base  = (bf16*)d_ws;
    bf16* q_ws  = base;                      // (b,h,s,d), pre-scaled
    bf16* k_ws  = base + 4 * MEG;            // (b,h,s,d)
    bf16* v_ws  = base + 8 * MEG;            // (b,h,d,s)  transposed
    bf16* ao_ws = base + 12 * MEG;           // (b,s,h,d): split-0 partial, then final
    bf16* xb    = base + 16 * MEG;           // bf16 inputs; reused as split-1 partial
    bf16* po1   = xb;                        // (b,s,h,d) partial O of split 1 (8 MB)
    bf16* wqb   = base + 20 * MEG;           // reused as l_ws after qkv_gemm
    float* l_ws = (float*)wqb;               // [split][bh][s] denominators (512 KB)
    bf16* wkb   = base + 21 * MEG;
    bf16* wvb   = base + 22 * MEG;
    bf16* wob   = base + 23 * MEG;

    cvt_kernel<<<dim3(4096), 256, 0, stream>>>(x, Wq, Wk, Wv, Wo, xb);
    qkv_gemm_kernel<<<dim3(24, 32), 256, 0, stream>>>(
        xb, wqb, bq, wkb, bk, wvb, bv, q_ws, k_ws, v_ws);
    attn_kernel<<<dim3(32, 16, 2), 512, 0, stream>>>(
        q_ws, k_ws, v_ws, ao_ws, po1, l_ws);
    combine_kernel<<<dim3(2048), 256, 0, stream>>>(ao_ws, po1, l_ws);
    out_gemm_kernel<<<dim3(8, 32), 256, 0, stream>>>(ao_ws, wob, bo, out);
}